// Round 7
// baseline (152.806 us; speedup 1.0000x reference)
//
#include <hip/hip_runtime.h>
#include <hip/hip_bf16.h>

// Shapes: x(8,16,4,64,64) f32, W(256,16,5,5) f32, b(1,1,8,32) f32
// out(8,32,8,64,64) f32.
//
// Verified reinterpretations (R1/R3/R4/R6 passing):
//   conv input  t2[n,a,h,w] = x[b0, fl&15, ci, fl>>10, (fl>>4)&63],
//     fl = a*4096 + h*64 + w, n = ci*8 + b0
//   votes flat (n,oc,y,x) reinterpreted by routing as (bv,civ,h,w,o,ao),
//     n = bv*4 + civ.
// Conv = implicit GEMM on v_mfma_f32_16x16x32_f16 (layouts m89/m120).
// R5 lesson: no conv+routing fusion (w-sparse out footprint -> 16x write amp).
// R6 lesson: 2-row conv tile -> 176 VGPR -> occupancy collapse; 1-row + deep
// prefetch instead (A-latency ~300cyc needs 2 steps of cover).

typedef _Float16 half8 __attribute__((ext_vector_type(8)));
typedef _Float16 half4v __attribute__((ext_vector_type(4)));
typedef float floatx4 __attribute__((ext_vector_type(4)));

#define EPSF 1e-7f

// Prep: blocks [0,256) = pack x->th (R4-proven); [256,672) = packw.
__global__ __launch_bounds__(256) void k_prep(const float* __restrict__ x,
                                              const float* __restrict__ W,
                                              _Float16* __restrict__ th,
                                              _Float16* __restrict__ Wp) {
  const int tid = threadIdx.x;
  if (blockIdx.x < 256) {
    __shared__ float lin[32 * 306 + 18];   // [m=32][a1 pad17][w1 pad18]
    const int bid = blockIdx.x;
    const int n   = bid >> 3;
    const int a0h = (bid >> 2) & 1;
    const int W0  = (bid & 3) * 16;
    const int ci = n >> 3, b0 = n & 7;
    const float* xb = x + b0 * 262144 + ci * 4096 + W0;
    for (int p = 0; p < 8; ++p) {
      int rr = p * 64 + (tid >> 2);
      int qq = (tid & 3) * 4;
      int a1 = rr >> 5, m = rr & 31;
      float4 v = *(const float4*)(xb + a1 * 16384 + (a0h * 32 + m) * 64 + qq);
      float* d = lin + m * 306 + a1 * 18 + qq;
      d[0] = v.x; d[1] = v.y; d[2] = v.z; d[3] = v.w;
    }
    __syncthreads();
    _Float16* tb = th + (size_t)n * 65536 + a0h * 32768 + W0 * 128;
    for (int hh = 0; hh < 4; ++hh) {
      int w1 = tid >> 4, a1 = tid & 15;
      half8 v;
#pragma unroll
      for (int j = 0; j < 8; ++j)
        v[j] = (_Float16)lin[(j * 4 + hh) * 306 + a1 * 18 + w1];
      *(half8*)(tb + hh * 8192 + w1 * 128 + a1 * 8) = v;
    }
  } else {
    int id = (blockIdx.x - 256) * 256 + tid;    // 106,496 = 26*4096
    int a  = id & 15;
    int oc = (id >> 4) & 255;
    int kk = id >> 12;
    Wp[id] = (kk < 25) ? (_Float16)W[oc * 400 + a * 25 + kk] : (_Float16)0.0f;
  }
}

// Conv (1-row, R3 mapping) + 2-deep A prefetch + 1-deep B prefetch.
// Block (y, n); 4 waves; wave wv = oc [wv*64,+64) x 64 x. 16 MFMA/K-step.
__global__ __launch_bounds__(256, 3) void k_conv(
    const _Float16* __restrict__ th, const _Float16* __restrict__ Wp,
    _Float16* __restrict__ votes) {
  __shared__ _Float16 slab[5440];     // [a0h=2][rr=5][col=68][8a]  10.6 KB
  const int y = blockIdx.x;           // 0..63
  const int n = blockIdx.y;           // 0..31
  const int tid = threadIdx.x;

  for (int c = tid; c < 680; c += 256) {
    int ah  = c / 340;
    int rem = c - ah * 340;
    int rr  = rem / 68;
    int cc  = rem - rr * 68;
    int row = y + rr - 2;
    int col = cc - 2;
    half8 v = {};
    if (row >= 0 && row < 64 && col >= 0 && col < 64)
      v = *(const half8*)(th + (size_t)(((n * 2 + ah) * 64 + row) * 64 + col) * 8);
    *(half8*)(slab + c * 8) = v;
  }

  const int lane  = tid & 63;
  const int wv    = tid >> 6;
  const int col16 = lane & 15;
  const int quad  = lane >> 4;      // 0..3
  const int t     = quad >> 1;      // tap-within-pair
  const int a0h   = quad & 1;       // atom-half
  const int m0    = wv * 64;

  floatx4 acc[4][4] = {};

  // A plane for step s is (2s+t); plane 25 is all-zero (packw) so A never
  // needs clamping; only the B address clamps (contribution zeroed by A).
  const _Float16* wb = Wp + (size_t)t * 4096 + (m0 + col16) * 16 + a0h * 8;
  half8 af[4], a1[4], a2[4], bf[4], b1[4];
#pragma unroll
  for (int oct = 0; oct < 4; ++oct) {
    af[oct] = *(const half8*)(wb + oct * 256);            // plane t
    a1[oct] = *(const half8*)(wb + 8192 + oct * 256);     // plane 2+t
  }

  __syncthreads();

  {
    int kkb = t;
    int ky = kkb / 5, kx = kkb - ky * 5;
    const _Float16* lb = slab + (a0h * 340 + ky * 68 + col16 + kx) * 8;
#pragma unroll
    for (int xt = 0; xt < 4; ++xt)
      bf[xt] = *(const half8*)(lb + xt * 128);
  }

  for (int s = 0; s < 13; ++s) {
    int s2 = (s + 2 < 13) ? s + 2 : 12;
#pragma unroll
    for (int oct = 0; oct < 4; ++oct)
      a2[oct] = *(const half8*)(wb + (size_t)s2 * 8192 + oct * 256);
    int kkb1 = 2 * (s + 1) + t; if (kkb1 > 24) kkb1 = 24;
    int ky1 = kkb1 / 5, kx1 = kkb1 - ky1 * 5;
    const _Float16* lb1 = slab + (a0h * 340 + ky1 * 68 + col16 + kx1) * 8;
#pragma unroll
    for (int xt = 0; xt < 4; ++xt)
      b1[xt] = *(const half8*)(lb1 + xt * 128);
#pragma unroll
    for (int oct = 0; oct < 4; ++oct)
#pragma unroll
      for (int xt = 0; xt < 4; ++xt)
        acc[oct][xt] = __builtin_amdgcn_mfma_f32_16x16x32_f16(
            af[oct], bf[xt], acc[oct][xt], 0, 0, 0);
#pragma unroll
    for (int oct = 0; oct < 4; ++oct) { af[oct] = a1[oct]; a1[oct] = a2[oct]; }
#pragma unroll
    for (int xt = 0; xt < 4; ++xt) bf[xt] = b1[xt];
  }

  // D[row=quad*4+r][col=col16] -> votes[n, oc, y, x]
  _Float16* vbase = votes + (size_t)n * 1048576 + y * 64;
#pragma unroll
  for (int oct = 0; oct < 4; ++oct)
#pragma unroll
    for (int xt = 0; xt < 4; ++xt)
#pragma unroll
      for (int r = 0; r < 4; ++r) {
        int oc = m0 + oct * 16 + quad * 4 + r;
        int xx = xt * 16 + col16;
        vbase[(size_t)oc * 4096 + xx] = (_Float16)acc[oct][xt][r];
      }
}

// Routing v3: block = (bv, h, 32 w). Acts kept in registers for all 8
// positions/wave; two f32 LDS phases (18.9 KB) for coalesced writeout.
__global__ __launch_bounds__(256) void k_routing3(
    const _Float16* __restrict__ votes, const float* __restrict__ bias,
    float* __restrict__ out) {
  __shared__ float so[128 * 37];        // 18.9 KB
  const int tid  = threadIdx.x;
  const int lane = tid & 63;
  const int wv   = tid >> 6;
  const int bid  = blockIdx.x;          // 1024
  const int bv = bid >> 7;
  const int h  = (bid >> 1) & 63;
  const int W0 = (bid & 1) * 32;

  float4 bia = *(const float4*)(bias + lane * 4);
  const int o = lane >> 3;
  const int m = lane & 7;               // a0 = m*4

  float act[8][4];

  const _Float16* vb0 = votes + (size_t)bv * 4194304 + h * 16384
                        + (W0 + wv * 8) * 256 + lane * 4;
  half4v vn[4];
#pragma unroll
  for (int i = 0; i < 4; ++i)
    vn[i] = *(const half4v*)(vb0 + (size_t)i * 1048576);

  for (int k = 0; k < 8; ++k) {
    float4 v[4];
#pragma unroll
    for (int i = 0; i < 4; ++i)
      v[i] = make_float4((float)vn[i].x, (float)vn[i].y,
                         (float)vn[i].z, (float)vn[i].w);
    if (k < 7) {
#pragma unroll
      for (int i = 0; i < 4; ++i)
        vn[i] = *(const half4v*)(vb0 + (k + 1) * 256 + (size_t)i * 1048576);
    }

    float logit[4] = {0.f, 0.f, 0.f, 0.f};
#pragma unroll
    for (int r = 0; r < 3; ++r) {
      float route[4];
#pragma unroll
      for (int i = 0; i < 4; ++i) {
        float mx = logit[i];
        mx = fmaxf(mx, __shfl_xor(mx, 8, 64));
        mx = fmaxf(mx, __shfl_xor(mx, 16, 64));
        mx = fmaxf(mx, __shfl_xor(mx, 32, 64));
        float e = __expf(logit[i] - mx);
        float s = e;
        s += __shfl_xor(s, 8, 64);
        s += __shfl_xor(s, 16, 64);
        s += __shfl_xor(s, 32, 64);
        route[i] = e / s;
      }
      float pr[4] = {bia.x, bia.y, bia.z, bia.w};
#pragma unroll
      for (int i = 0; i < 4; ++i) {
        pr[0] = fmaf(route[i], v[i].x, pr[0]);
        pr[1] = fmaf(route[i], v[i].y, pr[1]);
        pr[2] = fmaf(route[i], v[i].z, pr[2]);
        pr[3] = fmaf(route[i], v[i].w, pr[3]);
      }
      float sq = pr[0]*pr[0] + pr[1]*pr[1] + pr[2]*pr[2] + pr[3]*pr[3];
      sq += __shfl_xor(sq, 1, 64);
      sq += __shfl_xor(sq, 2, 64);
      sq += __shfl_xor(sq, 4, 64);
      float scale = sq / (1.f + sq) / sqrtf(sq + EPSF);
#pragma unroll
      for (int j = 0; j < 4; ++j) act[k][j] = pr[j] * scale;

      if (r < 2) {
#pragma unroll
        for (int i = 0; i < 4; ++i) {
          float ag = v[i].x*act[k][0] + v[i].y*act[k][1]
                   + v[i].z*act[k][2] + v[i].w*act[k][3];
          ag += __shfl_xor(ag, 1, 64);
          ag += __shfl_xor(ag, 2, 64);
          ag += __shfl_xor(ag, 4, 64);
          logit[i] += ag;
        }
      }
    }
  }

  // Two staging phases: phase ph covers j = 2*ph, 2*ph+1.
  float* ob = out + (size_t)bv * 1048576 + h * 64 + W0;
#pragma unroll
  for (int ph = 0; ph < 2; ++ph) {
    if (ph) __syncthreads();            // protect so[] reuse
#pragma unroll
    for (int k = 0; k < 8; ++k)
#pragma unroll
      for (int jj = 0; jj < 2; ++jj) {
        int rc = m * 16 + jj * 8 + o;   // compact row
        so[rc * 37 + wv * 8 + k] = act[k][2 * ph + jj];
      }
    __syncthreads();
    for (int p = 0; p < 4; ++p) {
      int rc = p * 32 + (tid >> 3);     // 0..127
      int mm = rc >> 4, jj = (rc >> 3) & 1, oo = rc & 7;
      int rg = mm * 32 + (2 * ph + jj) * 8 + oo;   // global row a*8+o
      int w0 = (tid & 7) * 4;
      const float* sp = so + rc * 37 + w0;
      float4 val = make_float4(sp[0], sp[1], sp[2], sp[3]);
      *(float4*)(ob + (size_t)rg * 4096 + w0) = val;
    }
  }
}

extern "C" void kernel_launch(void* const* d_in, const int* in_sizes, int n_in,
                              void* d_out, int out_size, void* d_ws, size_t ws_size,
                              hipStream_t stream) {
  const float* x  = (const float*)d_in[0];
  const float* W  = (const float*)d_in[1];
  const float* b  = (const float*)d_in[2];
  float* out = (float*)d_out;

  _Float16* th    = (_Float16*)d_ws;            // 2,097,152 halves (4 MB)
  _Float16* Wp    = th + 2097152;               // 106,496 halves (208 KB)
  _Float16* votes = Wp + 106496;                // 33,554,432 halves (64 MB)

  k_prep<<<672, 256, 0, stream>>>(x, W, th, Wp);
  k_conv<<<dim3(64, 32), 256, 0, stream>>>(th, Wp, votes);
  k_routing3<<<1024, 256, 0, stream>>>(votes, b, out);
}

// Round 8
// 144.649 us; speedup vs baseline: 1.0564x; 1.0564x over previous
//
#include <hip/hip_runtime.h>
#include <hip/hip_bf16.h>

// Shapes: x(8,16,4,64,64) f32, W(256,16,5,5) f32, b(1,1,8,32) f32
// out(8,32,8,64,64) f32.
//
// Verified reinterpretations (R1/R3/R4/R6/R7 passing):
//   conv input  t2[n,a,h,w] = x[b0, fl&15, ci, fl>>10, (fl>>4)&63],
//     fl = a*4096 + h*64 + w, n = ci*8 + b0
//   votes flat (n,oc,y,x) reinterpreted by routing as (bv,civ,h,w,o,ao),
//     n = bv*4 + civ.
// Conv = implicit GEMM on v_mfma_f32_16x16x32_f16 (layouts m89/m120).
// R5: no conv+routing fusion (w-sparse out -> 16x write amp).
// R6: 2-row tile -> VGPR collapse. R7: epilogue was 64 scalar 2B stores/thread
// -> swap mfma operands so D rows = x (4 consecutive halves/lane = 8B stores).

typedef _Float16 half8 __attribute__((ext_vector_type(8)));
typedef _Float16 half4v __attribute__((ext_vector_type(4)));
typedef float floatx4 __attribute__((ext_vector_type(4)));

#define EPSF 1e-7f

// thp: padded (n, a0h, row 0..67, col 0..67, 8a) f16; halo = input +-2, zeroed
// by hipMemsetAsync before k_prep fills the interior.
// chunk(n,ah,row,col) = ((n*2+ah)*68 + row)*68 + col   (8 halves per chunk)

// Prep: blocks [0,256) pack x -> thp interior; [256,672) packw.
__global__ __launch_bounds__(256) void k_prep(const float* __restrict__ x,
                                              const float* __restrict__ W,
                                              _Float16* __restrict__ thp,
                                              _Float16* __restrict__ Wp) {
  const int tid = threadIdx.x;
  if (blockIdx.x < 256) {
    __shared__ float lin[32 * 306 + 18];   // [m=32][a1 pad17][w1 pad18]
    const int bid = blockIdx.x;
    const int n   = bid >> 3;
    const int a0h = (bid >> 2) & 1;
    const int W0  = (bid & 3) * 16;
    const int ci = n >> 3, b0 = n & 7;
    const float* xb = x + b0 * 262144 + ci * 4096 + W0;
    for (int p = 0; p < 8; ++p) {
      int rr = p * 64 + (tid >> 2);
      int qq = (tid & 3) * 4;
      int a1 = rr >> 5, m = rr & 31;
      float4 v = *(const float4*)(xb + a1 * 16384 + (a0h * 32 + m) * 64 + qq);
      float* d = lin + m * 306 + a1 * 18 + qq;
      d[0] = v.x; d[1] = v.y; d[2] = v.z; d[3] = v.w;
    }
    __syncthreads();
    // emit: thread (w1=tid>>4, a1=tid&15); (h,w) from the R4-verified map:
    //   h = hh*16 + ((W0+w1)>>2), w = ((W0+w1)&3)*16 + a1
    for (int hh = 0; hh < 4; ++hh) {
      int w1 = tid >> 4, a1 = tid & 15;
      int h = hh * 16 + ((W0 + w1) >> 2);
      int w = ((W0 + w1) & 3) * 16 + a1;
      half8 v;
#pragma unroll
      for (int j = 0; j < 8; ++j)
        v[j] = (_Float16)lin[(j * 4 + hh) * 306 + a1 * 18 + w1];
      size_t chunk = ((size_t)(n * 2 + a0h) * 68 + (h + 2)) * 68 + (w + 2);
      *(half8*)(thp + chunk * 8) = v;
    }
  } else {
    int id = (blockIdx.x - 256) * 256 + tid;    // 106,496 = 26*4096
    int a  = id & 15;
    int oc = (id >> 4) & 255;
    int kk = id >> 12;
    Wp[id] = (kk < 25) ? (_Float16)W[oc * 400 + a * 25 + kk] : (_Float16)0.0f;
  }
}

// Conv v4: block (y, n); 4 waves; wave wv: M = 64 x-pixels, N = oc
// [wv*64,+64), 4x4 tiles. mfma(A=pixels, B=weights) -> D[row=x][col=oc]
// -> 8B stores. Weights 2-deep prefetch (L2 latency), pixels 1-deep (LDS).
__global__ __launch_bounds__(256) void k_conv(
    const _Float16* __restrict__ thp, const _Float16* __restrict__ Wp,
    _Float16* __restrict__ votes) {
  __shared__ _Float16 slab[5440];     // [ah=2][rr=5][cc=68][8a]  10.6 KB
  const int y = blockIdx.x;           // 0..63
  const int n = blockIdx.y;           // 0..31
  const int tid = threadIdx.x;

  // Branch-free staging: padded rows y..y+4 (= input y-2..y+2), cols 0..67.
  const size_t base0 = (size_t)(n * 2) * 36992 + (size_t)y * 544;
  for (int c = tid; c < 680; c += 256) {
    int ah  = (c >= 340);
    int rem = c - ah * 340;
    *(half8*)(slab + c * 8) =
        *(const half8*)(thp + base0 + (size_t)ah * 36992 + rem * 8);
  }

  const int lane  = tid & 63;
  const int wv    = tid >> 6;
  const int col16 = lane & 15;
  const int quad  = lane >> 4;      // 0..3
  const int t     = quad >> 1;      // tap-within-pair
  const int a0h   = quad & 1;       // atom-half
  const int m0    = wv * 64;        // oc base

  floatx4 acc[4][4] = {};           // [xt][oct]

  // Weight B-frag base: plane(2s+t) -> wb + s*8192; plane 25 is zeros.
  const _Float16* wb = Wp + (size_t)t * 4096 + (m0 + col16) * 16 + a0h * 8;
  half8 wf[4], wf1[4], wf2[4], pf[4], pf1[4];
#pragma unroll
  for (int oct = 0; oct < 4; ++oct) {
    wf[oct]  = *(const half8*)(wb + oct * 256);
    wf1[oct] = *(const half8*)(wb + 8192 + oct * 256);
  }

  __syncthreads();

  // Pixel A-frags for s=0: tap kkb = t (ky=0, kx=t).
#pragma unroll
  for (int xt = 0; xt < 4; ++xt)
    pf[xt] = *(const half8*)(slab + (a0h * 340 + xt * 16 + col16 + t) * 8);

  for (int s = 0; s < 13; ++s) {
    int s2 = (s + 2 < 13) ? s + 2 : 12;
#pragma unroll
    for (int oct = 0; oct < 4; ++oct)
      wf2[oct] = *(const half8*)(wb + (size_t)s2 * 8192 + oct * 256);
    int kkb1 = 2 * (s + 1) + t; if (kkb1 > 24) kkb1 = 24;  // pixel addr clamp
    int ky1 = kkb1 / 5, kx1 = kkb1 - ky1 * 5;
    const _Float16* lb1 = slab + (a0h * 340 + ky1 * 68 + col16 + kx1) * 8;
#pragma unroll
    for (int xt = 0; xt < 4; ++xt)
      pf1[xt] = *(const half8*)(lb1 + xt * 128);
#pragma unroll
    for (int xt = 0; xt < 4; ++xt)
#pragma unroll
      for (int oct = 0; oct < 4; ++oct)
        acc[xt][oct] = __builtin_amdgcn_mfma_f32_16x16x32_f16(
            pf[xt], wf[oct], acc[xt][oct], 0, 0, 0);
#pragma unroll
    for (int oct = 0; oct < 4; ++oct) { wf[oct] = wf1[oct]; wf1[oct] = wf2[oct]; }
#pragma unroll
    for (int xt = 0; xt < 4; ++xt) pf[xt] = pf1[xt];
  }

  // D[row = x = xt*16 + quad*4 + r][col = oc = oct*16 + col16]
  // -> votes[n, oc, y, x]: 4 consecutive x per lane = one 8B store.
  _Float16* vbase = votes + (size_t)n * 1048576 + y * 64;
#pragma unroll
  for (int oct = 0; oct < 4; ++oct) {
    int oc = m0 + oct * 16 + col16;
#pragma unroll
    for (int xt = 0; xt < 4; ++xt) {
      half4v o4;
      o4.x = (_Float16)acc[xt][oct][0];
      o4.y = (_Float16)acc[xt][oct][1];
      o4.z = (_Float16)acc[xt][oct][2];
      o4.w = (_Float16)acc[xt][oct][3];
      *(half4v*)(vbase + (size_t)oc * 4096 + xt * 16 + quad * 4) = o4;
    }
  }
}

// Routing v4: block = (bv, h, 16 w); 4 waves x 4 positions. Iter-0 softmax
// replaced by exact 1/8; iters 1-2 use max-free softmax (|logit|<~16).
__global__ __launch_bounds__(256) void k_routing4(
    const _Float16* __restrict__ votes, const float* __restrict__ bias,
    float* __restrict__ out) {
  __shared__ float so[256 * 17];        // 17.0 KB
  const int tid  = threadIdx.x;
  const int lane = tid & 63;
  const int wv   = tid >> 6;
  const int bid  = blockIdx.x;          // 2048
  const int bv = bid >> 8;
  const int h  = (bid >> 2) & 63;
  const int W0 = (bid & 3) * 16;

  float4 bia = *(const float4*)(bias + lane * 4);
  const int o = lane >> 3;
  const int m = lane & 7;

  float act[4][4];

  const _Float16* vb0 = votes + (size_t)bv * 4194304 + h * 16384
                        + (W0 + wv * 4) * 256 + lane * 4;

#pragma unroll
  for (int k = 0; k < 4; ++k) {
    float4 v[4];
#pragma unroll
    for (int i = 0; i < 4; ++i) {
      half4v hv = *(const half4v*)(vb0 + k * 256 + (size_t)i * 1048576);
      v[i] = make_float4((float)hv.x, (float)hv.y, (float)hv.z, (float)hv.w);
    }

    // ---- r = 0: route = 1/8 exactly (softmax of zero logits) ----
    float pr[4] = {bia.x, bia.y, bia.z, bia.w};
#pragma unroll
    for (int i = 0; i < 4; ++i) {
      pr[0] = fmaf(0.125f, v[i].x, pr[0]);
      pr[1] = fmaf(0.125f, v[i].y, pr[1]);
      pr[2] = fmaf(0.125f, v[i].z, pr[2]);
      pr[3] = fmaf(0.125f, v[i].w, pr[3]);
    }
    float sq = pr[0]*pr[0] + pr[1]*pr[1] + pr[2]*pr[2] + pr[3]*pr[3];
    sq += __shfl_xor(sq, 1, 64);
    sq += __shfl_xor(sq, 2, 64);
    sq += __shfl_xor(sq, 4, 64);
    float scale = sq / (1.f + sq) / sqrtf(sq + EPSF);
    float a0 = pr[0]*scale, a1 = pr[1]*scale, a2 = pr[2]*scale, a3 = pr[3]*scale;

    float logit[4];
#pragma unroll
    for (int i = 0; i < 4; ++i) {
      float ag = v[i].x*a0 + v[i].y*a1 + v[i].z*a2 + v[i].w*a3;
      ag += __shfl_xor(ag, 1, 64);
      ag += __shfl_xor(ag, 2, 64);
      ag += __shfl_xor(ag, 4, 64);
      logit[i] = ag;
    }

    // ---- r = 1, 2 ----
#pragma unroll
    for (int r = 1; r < 3; ++r) {
      float route[4];
#pragma unroll
      for (int i = 0; i < 4; ++i) {
        float e = __expf(logit[i]);       // max-free: |logit| small
        float s = e;
        s += __shfl_xor(s, 8, 64);
        s += __shfl_xor(s, 16, 64);
        s += __shfl_xor(s, 32, 64);
        route[i] = e / s;
      }
      pr[0] = bia.x; pr[1] = bia.y; pr[2] = bia.z; pr[3] = bia.w;
#pragma unroll
      for (int i = 0; i < 4; ++i) {
        pr[0] = fmaf(route[i], v[i].x, pr[0]);
        pr[1] = fmaf(route[i], v[i].y, pr[1]);
        pr[2] = fmaf(route[i], v[i].z, pr[2]);
        pr[3] = fmaf(route[i], v[i].w, pr[3]);
      }
      sq = pr[0]*pr[0] + pr[1]*pr[1] + pr[2]*pr[2] + pr[3]*pr[3];
      sq += __shfl_xor(sq, 1, 64);
      sq += __shfl_xor(sq, 2, 64);
      sq += __shfl_xor(sq, 4, 64);
      scale = sq / (1.f + sq) / sqrtf(sq + EPSF);
      a0 = pr[0]*scale; a1 = pr[1]*scale; a2 = pr[2]*scale; a3 = pr[3]*scale;

      if (r == 1) {
#pragma unroll
        for (int i = 0; i < 4; ++i) {
          float ag = v[i].x*a0 + v[i].y*a1 + v[i].z*a2 + v[i].w*a3;
          ag += __shfl_xor(ag, 1, 64);
          ag += __shfl_xor(ag, 2, 64);
          ag += __shfl_xor(ag, 4, 64);
          logit[i] += ag;
        }
      }
    }
    act[k][0] = a0; act[k][1] = a1; act[k][2] = a2; act[k][3] = a3;
  }

  // Stage to LDS, then coalesced writeout: 256 (a,o) rows x 16 w floats.
#pragma unroll
  for (int k = 0; k < 4; ++k)
#pragma unroll
    for (int j = 0; j < 4; ++j)
      so[((m * 4 + j) * 8 + o) * 17 + wv * 4 + k] = act[k][j];
  __syncthreads();

  float* ob = out + (size_t)bv * 1048576 + h * 64 + W0;
  for (int p = 0; p < 4; ++p) {
    int rg = p * 64 + (tid >> 2);       // 0..255 = a*8+o
    int w0 = (tid & 3) * 4;
    const float* sp = so + rg * 17 + w0;
    float4 val = make_float4(sp[0], sp[1], sp[2], sp[3]);
    *(float4*)(ob + (size_t)rg * 4096 + w0) = val;
  }
}

extern "C" void kernel_launch(void* const* d_in, const int* in_sizes, int n_in,
                              void* d_out, int out_size, void* d_ws, size_t ws_size,
                              hipStream_t stream) {
  const float* x  = (const float*)d_in[0];
  const float* W  = (const float*)d_in[1];
  const float* b  = (const float*)d_in[2];
  float* out = (float*)d_out;

  _Float16* thp   = (_Float16*)d_ws;            // 2,367,488 halves (4.52 MB)
  _Float16* Wp    = thp + 2367488;              // 106,496 halves (208 KB)
  _Float16* votes = Wp + 106496;                // 33,554,432 halves (64 MB)

  hipMemsetAsync(thp, 0, 2367488 * sizeof(_Float16), stream);  // halo zeros
  k_prep<<<672, 256, 0, stream>>>(x, W, thp, Wp);
  k_conv<<<dim3(64, 32), 256, 0, stream>>>(thp, Wp, votes);
  k_routing4<<<2048, 256, 0, stream>>>(votes, b, out);
}